// Round 5
// baseline (90.089 us; speedup 1.0000x reference)
//
#include <hip/hip_runtime.h>

#define NB 16
#define NA 98304
#define NM 32
#define NS 32
#define BLKI 48         // k_iou blocks/image: 256 thr x 8 anchors = 2048 -> 768 total = 3/CU
#define BLKP 96         // k_push blocks/image: 256 thr x 4 anchors = 1024
#define TARGET 256      // expected kept candidates per list (superset of top-64, ~12 sigma margin)
#define GCAP 1024       // global candidate capacity per image per list
#define BCAP 512        // per-block LDS compaction capacity

typedef unsigned int u32;
typedef unsigned long long u64;

static_assert(NA == BLKI * 256 * 8, "coverage iou");
static_assert(NA == BLKP * 256 * 4, "coverage push");

struct WS {
  u64   pos_key[NB * GCAP];
  u64   neg_key[NB * GCAP];
  float iou_max[NB * NA];
  float blk_max[NB * BLKI];
  int   blk_nneg[NB * BLKI];
  int   blk_npos[NB * BLKI];
  float thresh[NB], cut_pos[NB], cut_neg[NB];
  int   n_neg[NB], n_pos07[NB], ge07[NB];
  u32   keys[NB][4];
  int   pos_cnt[NB], neg_cnt[NB];
  u32   cls_bits[NB], reg_bits[NB];
  int   done;
};

__device__ __forceinline__ u32 rotl32(u32 v, int d) { return (v << d) | (v >> (32 - d)); }

// Threefry-2x32, 20 rounds, exactly as jax/_src/prng.py
__device__ __forceinline__ void threefry2x32(u32 k0, u32 k1, u32 x0, u32 x1, u32& o0, u32& o1) {
  u32 k2 = k0 ^ k1 ^ 0x1BD11BDAu;
  x0 += k0; x1 += k1;
  x0 += x1; x1 = rotl32(x1, 13); x1 ^= x0;
  x0 += x1; x1 = rotl32(x1, 15); x1 ^= x0;
  x0 += x1; x1 = rotl32(x1, 26); x1 ^= x0;
  x0 += x1; x1 = rotl32(x1, 6);  x1 ^= x0;
  x0 += k1; x1 += k2 + 1u;
  x0 += x1; x1 = rotl32(x1, 17); x1 ^= x0;
  x0 += x1; x1 = rotl32(x1, 29); x1 ^= x0;
  x0 += x1; x1 = rotl32(x1, 16); x1 ^= x0;
  x0 += x1; x1 = rotl32(x1, 24); x1 ^= x0;
  x0 += k2; x1 += k0 + 2u;
  x0 += x1; x1 = rotl32(x1, 13); x1 ^= x0;
  x0 += x1; x1 = rotl32(x1, 15); x1 ^= x0;
  x0 += x1; x1 = rotl32(x1, 26); x1 ^= x0;
  x0 += x1; x1 = rotl32(x1, 6);  x1 ^= x0;
  x0 += k0; x1 += k1 + 3u;
  x0 += x1; x1 = rotl32(x1, 17); x1 ^= x0;
  x0 += x1; x1 = rotl32(x1, 29); x1 ^= x0;
  x0 += x1; x1 = rotl32(x1, 16); x1 ^= x0;
  x0 += x1; x1 = rotl32(x1, 24); x1 ^= x0;
  x0 += k1; x1 += k2 + 4u;
  x0 += x1; x1 = rotl32(x1, 13); x1 ^= x0;
  x0 += x1; x1 = rotl32(x1, 15); x1 ^= x0;
  x0 += x1; x1 = rotl32(x1, 26); x1 ^= x0;
  x0 += x1; x1 = rotl32(x1, 6);  x1 ^= x0;
  x0 += k2; x1 += k0 + 5u;
  o0 = x0; o1 = x1;
}

// partitionable random_bits(32) -> uniform(0.1, 1.0), bit-matching jax _uniform
__device__ __forceinline__ float tf_uniform(u32 k0, u32 k1, u32 idx) {
  u32 o0, o1;
  threefry2x32(k0, k1, 0u, idx, o0, o1);
  u32 bits = o0 ^ o1;
  float f = __uint_as_float((bits >> 9) | 0x3F800000u) - 1.0f;  // [0,1)
  float u = __fadd_rn(__fmul_rn(f, (1.0f - 0.1f)), 0.1f);
  return fmaxf(0.1f, u);
}

__device__ __forceinline__ u64 pack_key(float u, u32 a) {
  return ((u64)__float_as_uint(u) << 32) | (u64)(u32)(~a);
}

// K1: max-IoU per anchor (value only; argmax recomputed later for selected
// positives) + per-block stats. Running max kept as exact fraction (bi,bu);
// cross-multiplication compare; ONE division per anchor at the end.
// ua eps-clamp dropped: areas >= ~255 by construction => clamp is a bit-exact no-op.
__global__ __launch_bounds__(256) void k_iou(const float* __restrict__ anchors,
                                             const float* __restrict__ ann,
                                             WS* __restrict__ ws) {
  int b = blockIdx.y;
  int tid = threadIdx.x;
  int a0 = (blockIdx.x * 256 + tid) * 8;
  __shared__ float bx1[NM], by1[NM], bx2[NM], by2[NM], barea[NM];
  __shared__ float wmax[4];
  __shared__ int wneg[4], wpos[4];
  if (tid < NM) {
    int m = tid;
    const float* p = ann + ((size_t)b * NM + m) * 5;
    float x1 = fminf(fmaxf(p[0], 0.0f), 512.0f);
    float y1 = fminf(fmaxf(p[1], 0.0f), 512.0f);
    float x2 = fminf(fmaxf(p[2], 0.0f), 512.0f);
    float y2 = fminf(fmaxf(p[3], 0.0f), 512.0f);
    bx1[m] = x1; by1[m] = y1; bx2[m] = x2; by2[m] = y2;
    barea[m] = __fmul_rn(__fsub_rn(x2, x1), __fsub_rn(y2, y1));
  }
  __syncthreads();

  const float4* a4 = (const float4*)anchors;
  float4 ap[8];
  float aarea[8], bi[8], bu[8];
#pragma unroll
  for (int k = 0; k < 8; k++) {
    ap[k] = a4[a0 + k];
    aarea[k] = __fmul_rn(__fsub_rn(ap[k].z, ap[k].x), __fsub_rn(ap[k].w, ap[k].y));
    bi[k] = -1.0f;   // q = -1/1: first box always wins
    bu[k] = 1.0f;
  }
  for (int m = 0; m < NM; m++) {
    float x1 = bx1[m], y1 = by1[m], x2 = bx2[m], y2 = by2[m], ar = barea[m];
#pragma unroll
    for (int k = 0; k < 8; k++) {
      float iw = fmaxf(__fsub_rn(fminf(ap[k].z, x2), fmaxf(ap[k].x, x1)), 0.0f);
      float ih = fmaxf(__fsub_rn(fminf(ap[k].w, y2), fmaxf(ap[k].y, y1)), 0.0f);
      float inter = __fmul_rn(iw, ih);
      float ua = __fsub_rn(__fadd_rn(aarea[k], ar), inter);  // >= ~255 always
      // inter/ua > bi/bu  <=>  inter*bu > bi*ua  (exact sign compare)
      bool upd = __fmul_rn(inter, bu[k]) > __fmul_rn(bi[k], ua);
      bi[k] = upd ? inter : bi[k];
      bu[k] = upd ? ua : bu[k];
    }
  }
  float best[8];
#pragma unroll
  for (int k = 0; k < 8; k++) best[k] = __fdiv_rn(bi[k], bu[k]);

  size_t o = (size_t)b * NA + a0;
  *(float4*)&ws->iou_max[o]     = make_float4(best[0], best[1], best[2], best[3]);
  *(float4*)&ws->iou_max[o + 4] = make_float4(best[4], best[5], best[6], best[7]);

  float lmax = -1.0f;
  int cneg = 0, cpos = 0;
#pragma unroll
  for (int k = 0; k < 8; k++) {
    lmax = fmaxf(lmax, best[k]);
    cneg += (best[k] < 0.4f && best[k] >= 0.1f) ? 1 : 0;
    cpos += (best[k] >= 0.7f) ? 1 : 0;
  }
  for (int s = 32; s > 0; s >>= 1) {
    lmax = fmaxf(lmax, __shfl_xor(lmax, s));
    cneg += __shfl_xor(cneg, s);
    cpos += __shfl_xor(cpos, s);
  }
  int wid = tid >> 6;
  if ((tid & 63) == 0) { wmax[wid] = lmax; wneg[wid] = cneg; wpos[wid] = cpos; }
  __syncthreads();
  if (tid < 4) {
    lmax = wmax[tid]; cneg = wneg[tid]; cpos = wpos[tid];
    for (int s = 2; s > 0; s >>= 1) {
      lmax = fmaxf(lmax, __shfl_xor(lmax, s));
      cneg += __shfl_xor(cneg, s);
      cpos += __shfl_xor(cpos, s);
    }
    if (tid == 0) {
      int oo = b * BLKI + blockIdx.x;
      ws->blk_max[oo] = lmax;
      ws->blk_nneg[oo] = cneg;
      ws->blk_npos[oo] = cpos;
    }
  }
}

// K2: single block; 16 lanes per image reduce blk stats; thresholds, cuts,
// PRNG keys; zero counters + done flag.
__global__ __launch_bounds__(256) void k_stats(WS* __restrict__ ws) {
  int tid = threadIdx.x;
  int b = tid >> 4, l = tid & 15;
  float m = -1.0f;
  int nn = 0, np = 0;
  for (int i = l; i < BLKI; i += 16) {
    m = fmaxf(m, ws->blk_max[b * BLKI + i]);
    nn += ws->blk_nneg[b * BLKI + i];
    np += ws->blk_npos[b * BLKI + i];
  }
  for (int s = 8; s > 0; s >>= 1) {
    m = fmaxf(m, __shfl_xor(m, s));
    nn += __shfl_xor(nn, s);
    np += __shfl_xor(np, s);
  }
  if (l == 0) {
    ws->thresh[b] = fminf(m, 0.7f);
    int ge = (m >= 0.7f) ? 1 : 0;
    ws->ge07[b] = ge;
    ws->n_neg[b] = nn;
    ws->n_pos07[b] = np;
    ws->cut_neg[b] = (nn <= TARGET) ? -1.0f : (1.0f - 0.9f * ((float)TARGET / (float)nn));
    ws->cut_pos[b] = (ge && np > TARGET) ? (1.0f - 0.9f * ((float)TARGET / (float)np)) : -1.0f;
    ws->pos_cnt[b] = 0;
    ws->neg_cnt[b] = 0;
    u32 o0, o1;
    threefry2x32(0u, 42u, 0u, (u32)(2 * b), o0, o1);
    ws->keys[b][0] = o0; ws->keys[b][1] = o1;
    threefry2x32(0u, 42u, 0u, (u32)(2 * b + 1), o0, o1);
    ws->keys[b][2] = o0; ws->keys[b][3] = o1;
  }
  if (tid == 0) ws->done = 0;
}

// K3: push kept candidates with per-block LDS compaction; 1 global atomic per block per list
__global__ __launch_bounds__(256) void k_push(WS* __restrict__ ws) {
  int b = blockIdx.y, tid = threadIdx.x;
  int a0 = (blockIdx.x * 256 + tid) * 4;
  __shared__ u64 pbuf[BCAP], nbuf[BCAP];
  __shared__ int pcnt, ncnt, pbase, nbase;
  if (tid == 0) { pcnt = 0; ncnt = 0; }
  __syncthreads();
  float thresh = ws->thresh[b];
  float cp = ws->cut_pos[b], cn = ws->cut_neg[b];
  u32 k0 = ws->keys[b][0], k1 = ws->keys[b][1];
  u32 k2 = ws->keys[b][2], k3 = ws->keys[b][3];
  float4 im4 = *(const float4*)&ws->iou_max[(size_t)b * NA + a0];
  float imv[4] = {im4.x, im4.y, im4.z, im4.w};
#pragma unroll
  for (int k = 0; k < 4; k++) {
    float im = imv[k];
    u32 a = (u32)(a0 + k);
    if (im >= thresh) {
      float u = tf_uniform(k0, k1, a);
      if (u >= cp) {
        int p = atomicAdd(&pcnt, 1);
        if (p < BCAP) pbuf[p] = pack_key(u, a);
      }
    }
    if (im < 0.4f && im >= 0.1f) {
      float u = tf_uniform(k2, k3, a);
      if (u >= cn) {
        int p = atomicAdd(&ncnt, 1);
        if (p < BCAP) nbuf[p] = pack_key(u, a);
      }
    }
  }
  __syncthreads();
  if (tid == 0) {
    pbase = (pcnt > 0) ? atomicAdd(&ws->pos_cnt[b], pcnt) : 0;  // unclamped: exact n_pos bookkeeping
    nbase = (ncnt > 0) ? atomicAdd(&ws->neg_cnt[b], ncnt) : 0;
  }
  __syncthreads();
  int pc = min(pcnt, BCAP), nc = min(ncnt, BCAP);
  for (int i = tid; i < pc; i += 256) { int g = pbase + i; if (g < GCAP) ws->pos_key[b * GCAP + g] = pbuf[i]; }
  for (int i = tid; i < nc; i += 256) { int g = nbase + i; if (g < GCAP) ws->neg_key[b * GCAP + g] = nbuf[i]; }
}

// K4: rank-based top-k selection + loss terms + fused final reduce (done-counter tail).
// rank(i) = #{j: key_j > key_i}; keys unique => rank<r is exactly lax.top_k's set,
// and slot[rank] reproduces selection order for bit-identical summation.
// Argmax for selected positives recomputed here with literal reference ops.
__global__ __launch_bounds__(256) void k_select(const float* __restrict__ cls,
                                                const float* __restrict__ reg,
                                                const float* __restrict__ anchors,
                                                const float* __restrict__ ann,
                                                const float* __restrict__ w,
                                                WS* __restrict__ ws,
                                                float* __restrict__ out) {
  int b = blockIdx.x, tid = threadIdx.x;
  __shared__ u64 pk[GCAP], nk[GCAP];
  __shared__ float bx1[NM], by1[NM], bx2[NM], by2[NM], barea[NM];
  __shared__ int selp[NS], seln[2 * NS];
  __shared__ float tpos[NS], treg[NS], tneg[2 * NS];

  if (tid < NM) {
    int m = tid;
    const float* p = ann + ((size_t)b * NM + m) * 5;
    float x1 = fminf(fmaxf(p[0], 0.0f), 512.0f);
    float y1 = fminf(fmaxf(p[1], 0.0f), 512.0f);
    float x2 = fminf(fmaxf(p[2], 0.0f), 512.0f);
    float y2 = fminf(fmaxf(p[3], 0.0f), 512.0f);
    bx1[m] = x1; by1[m] = y1; bx2[m] = x2; by2[m] = y2;
    barea[m] = __fmul_rn(__fsub_rn(x2, x1), __fsub_rn(y2, y1));
  }

  int mp = min(ws->pos_cnt[b], GCAP);
  int mn = min(ws->neg_cnt[b], GCAP);
  int n_pos = ws->ge07[b] ? ws->n_pos07[b] : ws->pos_cnt[b];
  int n_neg = ws->n_neg[b];
  int K = min(NS, n_pos);
  int rp = min(K, mp);
  int rn = min(min(2 * NS - K, n_neg), mn);

  int mpad = (mp + 255) & ~255;
  int npad = (mn + 255) & ~255;
  for (int i = tid; i < mpad; i += 256) pk[i] = (i < mp) ? ws->pos_key[b * GCAP + i] : 0ull;
  for (int i = tid; i < npad; i += 256) nk[i] = (i < mn) ? ws->neg_key[b * GCAP + i] : 0ull;
  if (tid < NS) { tpos[tid] = 0.0f; treg[tid] = 0.0f; }
  if (tid < 2 * NS) tneg[tid] = 0.0f;
  __syncthreads();

  // --- pos ranks (each thread owns up to GCAP/256 candidates; j-sweep shared) ---
  {
    u64 ck[GCAP / 256]; int cr[GCAP / 256];
    int nc = mpad >> 8;
#pragma unroll
    for (int c = 0; c < GCAP / 256; c++) { ck[c] = 0; cr[c] = 0; }
    for (int c = 0; c < nc; c++) ck[c] = pk[tid + (c << 8)];
    for (int j = 0; j < mp; j++) {
      u64 v = pk[j];
#pragma unroll
      for (int c = 0; c < GCAP / 256; c++) cr[c] += (v > ck[c]) ? 1 : 0;
    }
    for (int c = 0; c < nc; c++)
      if (ck[c] != 0 && cr[c] < rp) selp[cr[c]] = (int)(~(u32)ck[c]);
  }
  // --- neg ranks ---
  {
    u64 ck[GCAP / 256]; int cr[GCAP / 256];
    int nc = npad >> 8;
#pragma unroll
    for (int c = 0; c < GCAP / 256; c++) { ck[c] = 0; cr[c] = 0; }
    for (int c = 0; c < nc; c++) ck[c] = nk[tid + (c << 8)];
    for (int j = 0; j < mn; j++) {
      u64 v = nk[j];
#pragma unroll
      for (int c = 0; c < GCAP / 256; c++) cr[c] += (v > ck[c]) ? 1 : 0;
    }
    for (int c = 0; c < nc; c++)
      if (ck[c] != 0 && cr[c] < rn) seln[cr[c]] = (int)(~(u32)ck[c]);
  }
  __syncthreads();

  const float PLO = 1e-7f;
  const float PHI = (float)(1.0 - 1e-7);
  if (tid < rp) {
    int a = selp[tid];
    float p = cls[((size_t)b * NA + a) * 2 + 0];
    p = fminf(fmaxf(p, PLO), PHI);
    tpos[tid] = -logf(p);
    float4 apf = ((const float4*)anchors)[a];
    float ax1 = apf.x, ay1 = apf.y, ax2 = apf.z, ay2 = apf.w;
    float aarea = __fmul_rn(__fsub_rn(ax2, ax1), __fsub_rn(ay2, ay1));
    // recompute IoU row + first-argmax with literal reference ops
    float bestv = -1.0f; int bestm = 0;
    for (int m = 0; m < NM; m++) {
      float iw = fmaxf(__fsub_rn(fminf(ax2, bx2[m]), fmaxf(ax1, bx1[m])), 0.0f);
      float ih = fmaxf(__fsub_rn(fminf(ay2, by2[m]), fmaxf(ay1, by1[m])), 0.0f);
      float inter = __fmul_rn(iw, ih);
      float ua = fmaxf(__fsub_rn(__fadd_rn(aarea, barea[m]), inter), 1e-8f);
      float v = __fdiv_rn(inter, ua);
      if (v > bestv) { bestv = v; bestm = m; }
    }
    float aw_ = __fsub_rn(ax2, ax1), ah_ = __fsub_rn(ay2, ay1);
    float acx = __fadd_rn(ax1, __fmul_rn(0.5f, aw_));
    float acy = __fadd_rn(ay1, __fmul_rn(0.5f, ah_));
    float gx1 = bx1[bestm], gy1 = by1[bestm], gx2 = bx2[bestm], gy2 = by2[bestm];
    float gw = __fsub_rn(gx2, gx1), gh = __fsub_rn(gy2, gy1);
    float gcx = __fadd_rn(gx1, __fmul_rn(0.5f, gw));
    float gcy = __fadd_rn(gy1, __fmul_rn(0.5f, gh));
    gw = fmaxf(gw, 1.0f); gh = fmaxf(gh, 1.0f);
    float t0 = __fdiv_rn(__fdiv_rn(__fsub_rn(gcx, acx), aw_), 0.1f);
    float t1 = __fdiv_rn(__fdiv_rn(__fsub_rn(gcy, acy), ah_), 0.1f);
    float t2 = __fdiv_rn(logf(__fdiv_rn(gw, aw_)), 0.2f);
    float t3 = __fdiv_rn(logf(__fdiv_rn(gh, ah_)), 0.2f);
    const float* rg = reg + ((size_t)b * NA + a) * 4;
    float tt[4] = {t0, t1, t2, t3};
    float s = 0.0f;
#pragma unroll
    for (int c = 0; c < 4; c++) {
      float d = fabsf(__fsub_rn(tt[c], rg[c]));
      float q = (d <= (float)(1.0 / 9.0)) ? __fmul_rn(__fmul_rn(4.5f, d), d)
                                          : __fsub_rn(d, (float)(0.5 / 9.0));
      s = __fadd_rn(s, q);
    }
    treg[tid] = s;
  }
  if (tid < rn) {
    int a = seln[tid];
    bool ispos = false;
    for (int i = 0; i < rp; i++) if (selp[i] == a) ispos = true;
    if (!ispos) {
      float p = cls[((size_t)b * NA + a) * 2 + 1];
      p = fminf(fmaxf(p, PLO), PHI);
      tneg[tid] = -logf(p);
    }
  }
  __syncthreads();
  if (tid == 0) {
    float cs = 0.0f;
    for (int i = 0; i < NS; i++) cs = __fadd_rn(cs, tpos[i]);
    for (int i = 0; i < 2 * NS; i++) cs = __fadd_rn(cs, tneg[i]);
    float rs = 0.0f;
    for (int i = 0; i < NS; i++) rs = __fadd_rn(rs, treg[i]);
    float ci = __fdiv_rn(cs, 64.0f);
    float ri = __fdiv_rn(__fmul_rn(rs, w[b * 4 + 0]), 64.0f);
    // publish bits coherently (atomics are device-coherent across XCD L2s)
    atomicExch(&ws->cls_bits[b], __float_as_uint(ci));
    atomicExch(&ws->reg_bits[b], __float_as_uint(ri));
    __threadfence();
    int old = atomicAdd(&ws->done, 1);
    if (old == NB - 1) {  // last block: b-ordered deterministic reduce
      float c = 0.0f, r = 0.0f;
      for (int j = 0; j < NB; j++) {
        c = __fadd_rn(c, __uint_as_float(atomicOr(&ws->cls_bits[j], 0u)));
        r = __fadd_rn(r, __uint_as_float(atomicOr(&ws->reg_bits[j], 0u)));
      }
      out[0] = __fdiv_rn(c, 16.0f);
      out[1] = __fdiv_rn(r, 16.0f);
    }
  }
}

extern "C" void kernel_launch(void* const* d_in, const int* in_sizes, int n_in,
                              void* d_out, int out_size, void* d_ws, size_t ws_size,
                              hipStream_t stream) {
  const float* cls = (const float*)d_in[0];
  const float* reg = (const float*)d_in[1];
  const float* anchors = (const float*)d_in[2];  // (1, A, 4)
  const float* ann = (const float*)d_in[3];      // (B, M, 5)
  const float* w = (const float*)d_in[4];        // (B, 4)
  float* out = (float*)d_out;
  if (ws_size < sizeof(WS)) return;
  WS* ws = (WS*)d_ws;

  hipLaunchKernelGGL(k_iou, dim3(BLKI, NB), dim3(256), 0, stream, anchors, ann, ws);
  hipLaunchKernelGGL(k_stats, dim3(1), dim3(256), 0, stream, ws);
  hipLaunchKernelGGL(k_push, dim3(BLKP, NB), dim3(256), 0, stream, ws);
  hipLaunchKernelGGL(k_select, dim3(NB), dim3(256), 0, stream, cls, reg, anchors, ann, w, ws, out);
}

// Round 6
// 76.085 us; speedup vs baseline: 1.1841x; 1.1841x over previous
//
#include <hip/hip_runtime.h>

#define NB 16
#define NA 98304
#define NM 32
#define NS 32
#define BLKI 96         // blocks per image: 256 thr x 4 anchors = 1024
#define TARGET 256      // expected kept candidates per list (superset of top-64, ~12 sigma margin)
#define GCAP 1024       // global candidate capacity per image per list
#define BCAP 512        // per-block LDS compaction capacity

typedef unsigned int u32;
typedef unsigned long long u64;

static_assert(NA == BLKI * 256 * 4, "coverage");

struct WS {
  u64   pos_key[NB * GCAP];
  u64   neg_key[NB * GCAP];
  float iou_max[NB * NA];
  float blk_max[NB * BLKI];
  int   blk_nneg[NB * BLKI];
  int   blk_npos[NB * BLKI];
  int   pos_cnt[NB], neg_cnt[NB];
  u32   cls_bits[NB], reg_bits[NB];
  int   done;
};

__device__ __forceinline__ u32 rotl32(u32 v, int d) { return (v << d) | (v >> (32 - d)); }

// Threefry-2x32, 20 rounds, exactly as jax/_src/prng.py
__device__ __forceinline__ void threefry2x32(u32 k0, u32 k1, u32 x0, u32 x1, u32& o0, u32& o1) {
  u32 k2 = k0 ^ k1 ^ 0x1BD11BDAu;
  x0 += k0; x1 += k1;
  x0 += x1; x1 = rotl32(x1, 13); x1 ^= x0;
  x0 += x1; x1 = rotl32(x1, 15); x1 ^= x0;
  x0 += x1; x1 = rotl32(x1, 26); x1 ^= x0;
  x0 += x1; x1 = rotl32(x1, 6);  x1 ^= x0;
  x0 += k1; x1 += k2 + 1u;
  x0 += x1; x1 = rotl32(x1, 17); x1 ^= x0;
  x0 += x1; x1 = rotl32(x1, 29); x1 ^= x0;
  x0 += x1; x1 = rotl32(x1, 16); x1 ^= x0;
  x0 += x1; x1 = rotl32(x1, 24); x1 ^= x0;
  x0 += k2; x1 += k0 + 2u;
  x0 += x1; x1 = rotl32(x1, 13); x1 ^= x0;
  x0 += x1; x1 = rotl32(x1, 15); x1 ^= x0;
  x0 += x1; x1 = rotl32(x1, 26); x1 ^= x0;
  x0 += x1; x1 = rotl32(x1, 6);  x1 ^= x0;
  x0 += k0; x1 += k1 + 3u;
  x0 += x1; x1 = rotl32(x1, 17); x1 ^= x0;
  x0 += x1; x1 = rotl32(x1, 29); x1 ^= x0;
  x0 += x1; x1 = rotl32(x1, 16); x1 ^= x0;
  x0 += x1; x1 = rotl32(x1, 24); x1 ^= x0;
  x0 += k1; x1 += k2 + 4u;
  x0 += x1; x1 = rotl32(x1, 13); x1 ^= x0;
  x0 += x1; x1 = rotl32(x1, 15); x1 ^= x0;
  x0 += x1; x1 = rotl32(x1, 26); x1 ^= x0;
  x0 += x1; x1 = rotl32(x1, 6);  x1 ^= x0;
  x0 += k2; x1 += k0 + 5u;
  o0 = x0; o1 = x1;
}

// partitionable random_bits(32) -> uniform(0.1, 1.0), bit-matching jax _uniform
__device__ __forceinline__ float tf_uniform(u32 k0, u32 k1, u32 idx) {
  u32 o0, o1;
  threefry2x32(k0, k1, 0u, idx, o0, o1);
  u32 bits = o0 ^ o1;
  float f = __uint_as_float((bits >> 9) | 0x3F800000u) - 1.0f;  // [0,1)
  float u = __fadd_rn(__fmul_rn(f, (1.0f - 0.1f)), 0.1f);
  return fmaxf(0.1f, u);
}

__device__ __forceinline__ u64 pack_key(float u, u32 a) {
  return ((u64)__float_as_uint(u) << 32) | (u64)(u32)(~a);
}

// Per-image stats reduce from blk_* arrays (fmax / int-add: exactly associative,
// any order is bit-identical). Runs on wave 0; result broadcast by caller.
__device__ __forceinline__ void reduce_stats(const WS* ws, int b, int tid,
                                             float& m, int& nn, int& np) {
  m = -1.0f; nn = 0; np = 0;
  for (int i = tid; i < BLKI; i += 64) {
    m = fmaxf(m, ws->blk_max[b * BLKI + i]);
    nn += ws->blk_nneg[b * BLKI + i];
    np += ws->blk_npos[b * BLKI + i];
  }
  for (int s = 32; s > 0; s >>= 1) {
    m = fmaxf(m, __shfl_xor(m, s));
    nn += __shfl_xor(nn, s);
    np += __shfl_xor(np, s);
  }
}

// K1: max-IoU per anchor (value only) + per-block stats + counter zeroing.
// Running max as exact fraction (bi,bu), cross-mult compare, one div/anchor.
// ua eps-clamp dropped: areas >= ~255 by construction => clamp is bit-exact no-op.
__global__ __launch_bounds__(256) void k_iou(const float* __restrict__ anchors,
                                             const float* __restrict__ ann,
                                             WS* __restrict__ ws) {
  int b = blockIdx.y;
  int tid = threadIdx.x;
  int a0 = (blockIdx.x * 256 + tid) * 4;
  __shared__ float4 sbox[NM];
  __shared__ float sarea[NM];
  __shared__ float wmax[4];
  __shared__ int wneg[4], wpos[4];
  if (tid < NM) {
    const float* p = ann + ((size_t)b * NM + tid) * 5;
    float x1 = fminf(fmaxf(p[0], 0.0f), 512.0f);
    float y1 = fminf(fmaxf(p[1], 0.0f), 512.0f);
    float x2 = fminf(fmaxf(p[2], 0.0f), 512.0f);
    float y2 = fminf(fmaxf(p[3], 0.0f), 512.0f);
    sbox[tid] = make_float4(x1, y1, x2, y2);
    sarea[tid] = __fmul_rn(__fsub_rn(x2, x1), __fsub_rn(y2, y1));
  }
  if (blockIdx.x == 0 && tid == 0) {
    ws->pos_cnt[b] = 0;
    ws->neg_cnt[b] = 0;
    if (b == 0) ws->done = 0;
  }
  __syncthreads();

  const float4* a4 = (const float4*)anchors;
  float4 ap[4];
  float aarea[4], bi[4], bu[4];
#pragma unroll
  for (int k = 0; k < 4; k++) {
    ap[k] = a4[a0 + k];
    aarea[k] = __fmul_rn(__fsub_rn(ap[k].z, ap[k].x), __fsub_rn(ap[k].w, ap[k].y));
    bi[k] = -1.0f;   // q = -1/1: first box always wins
    bu[k] = 1.0f;
  }
  for (int m = 0; m < NM; m++) {
    float4 bx = sbox[m];
    float ar = sarea[m];
#pragma unroll
    for (int k = 0; k < 4; k++) {
      float iw = fmaxf(__fsub_rn(fminf(ap[k].z, bx.z), fmaxf(ap[k].x, bx.x)), 0.0f);
      float ih = fmaxf(__fsub_rn(fminf(ap[k].w, bx.w), fmaxf(ap[k].y, bx.y)), 0.0f);
      float inter = __fmul_rn(iw, ih);
      float ua = __fsub_rn(__fadd_rn(aarea[k], ar), inter);  // >= ~255 always
      bool upd = __fmul_rn(inter, bu[k]) > __fmul_rn(bi[k], ua);
      bi[k] = upd ? inter : bi[k];
      bu[k] = upd ? ua : bu[k];
    }
  }
  float best[4];
#pragma unroll
  for (int k = 0; k < 4; k++) best[k] = __fdiv_rn(bi[k], bu[k]);
  *(float4*)&ws->iou_max[(size_t)b * NA + a0] = make_float4(best[0], best[1], best[2], best[3]);

  float lmax = fmaxf(fmaxf(best[0], best[1]), fmaxf(best[2], best[3]));
  int cneg = 0, cpos = 0;
#pragma unroll
  for (int k = 0; k < 4; k++) {
    cneg += (best[k] < 0.4f && best[k] >= 0.1f) ? 1 : 0;
    cpos += (best[k] >= 0.7f) ? 1 : 0;
  }
  for (int s = 32; s > 0; s >>= 1) {
    lmax = fmaxf(lmax, __shfl_xor(lmax, s));
    cneg += __shfl_xor(cneg, s);
    cpos += __shfl_xor(cpos, s);
  }
  int wid = tid >> 6;
  if ((tid & 63) == 0) { wmax[wid] = lmax; wneg[wid] = cneg; wpos[wid] = cpos; }
  __syncthreads();
  if (tid < 4) {
    lmax = wmax[tid]; cneg = wneg[tid]; cpos = wpos[tid];
    for (int s = 2; s > 0; s >>= 1) {
      lmax = fmaxf(lmax, __shfl_xor(lmax, s));
      cneg += __shfl_xor(cneg, s);
      cpos += __shfl_xor(cpos, s);
    }
    if (tid == 0) {
      int o = b * BLKI + blockIdx.x;
      ws->blk_max[o] = lmax;
      ws->blk_nneg[o] = cneg;
      ws->blk_npos[o] = cpos;
    }
  }
}

// K2: push kept candidates; per-block inline stats recompute (no k_stats
// dispatch); per-block LDS compaction; 1 global atomic per block per list.
__global__ __launch_bounds__(256) void k_push(WS* __restrict__ ws) {
  int b = blockIdx.y, tid = threadIdx.x;
  int a0 = (blockIdx.x * 256 + tid) * 4;
  __shared__ u64 pbuf[BCAP], nbuf[BCAP];
  __shared__ int pcnt, ncnt, pbase, nbase;
  __shared__ float s_thresh, s_cp, s_cn;
  __shared__ u32 s_keys[4];
  if (tid == 0) { pcnt = 0; ncnt = 0; }
  if (tid < 64) {
    float m; int nn, np;
    reduce_stats(ws, b, tid, m, nn, np);
    if (tid == 0) {
      s_thresh = fminf(m, 0.7f);
      int ge = (m >= 0.7f) ? 1 : 0;
      s_cn = (nn <= TARGET) ? -1.0f : (1.0f - 0.9f * ((float)TARGET / (float)nn));
      s_cp = (ge && np > TARGET) ? (1.0f - 0.9f * ((float)TARGET / (float)np)) : -1.0f;
      u32 o0, o1;
      threefry2x32(0u, 42u, 0u, (u32)(2 * b), o0, o1);
      s_keys[0] = o0; s_keys[1] = o1;
      threefry2x32(0u, 42u, 0u, (u32)(2 * b + 1), o0, o1);
      s_keys[2] = o0; s_keys[3] = o1;
    }
  }
  __syncthreads();
  float thresh = s_thresh, cp = s_cp, cn = s_cn;
  u32 k0 = s_keys[0], k1 = s_keys[1], k2 = s_keys[2], k3 = s_keys[3];
  float4 im4 = *(const float4*)&ws->iou_max[(size_t)b * NA + a0];
  float imv[4] = {im4.x, im4.y, im4.z, im4.w};
#pragma unroll
  for (int k = 0; k < 4; k++) {
    float im = imv[k];
    u32 a = (u32)(a0 + k);
    if (im >= thresh) {
      float u = tf_uniform(k0, k1, a);
      if (u >= cp) {
        int p = atomicAdd(&pcnt, 1);
        if (p < BCAP) pbuf[p] = pack_key(u, a);
      }
    }
    if (im < 0.4f && im >= 0.1f) {
      float u = tf_uniform(k2, k3, a);
      if (u >= cn) {
        int p = atomicAdd(&ncnt, 1);
        if (p < BCAP) nbuf[p] = pack_key(u, a);
      }
    }
  }
  __syncthreads();
  if (tid == 0) {
    pbase = (pcnt > 0) ? atomicAdd(&ws->pos_cnt[b], pcnt) : 0;  // unclamped: exact n_pos bookkeeping
    nbase = (ncnt > 0) ? atomicAdd(&ws->neg_cnt[b], ncnt) : 0;
  }
  __syncthreads();
  int pc = min(pcnt, BCAP), nc = min(ncnt, BCAP);
  for (int i = tid; i < pc; i += 256) { int g = pbase + i; if (g < GCAP) ws->pos_key[b * GCAP + g] = pbuf[i]; }
  for (int i = tid; i < nc; i += 256) { int g = nbase + i; if (g < GCAP) ws->neg_key[b * GCAP + g] = nbuf[i]; }
}

// K3: rank-based top-k selection + loss + fused final reduce.
// rank(i) = #{j: key_j > key_i}; keys unique => rank<r is exactly lax.top_k's
// set AND order (value desc, index asc). Argmax for selected positives
// recomputed with literal reference ops. Tail: done-counter; winner does 32
// independent relaxed atomic loads (acquire via the ACQ_REL fetch_add).
__global__ __launch_bounds__(256) void k_select(const float* __restrict__ cls,
                                                const float* __restrict__ reg,
                                                const float* __restrict__ anchors,
                                                const float* __restrict__ ann,
                                                const float* __restrict__ w,
                                                WS* __restrict__ ws,
                                                float* __restrict__ out) {
  int b = blockIdx.x, tid = threadIdx.x;
  __shared__ u64 pk[GCAP], nk[GCAP];
  __shared__ float bx1[NM], by1[NM], bx2[NM], by2[NM], barea[NM];
  __shared__ int selp[NS], seln[2 * NS];
  __shared__ float tpos[NS], treg[NS], tneg[2 * NS];
  __shared__ int s_npos, s_nneg;

  if (tid < NM) {
    const float* p = ann + ((size_t)b * NM + tid) * 5;
    float x1 = fminf(fmaxf(p[0], 0.0f), 512.0f);
    float y1 = fminf(fmaxf(p[1], 0.0f), 512.0f);
    float x2 = fminf(fmaxf(p[2], 0.0f), 512.0f);
    float y2 = fminf(fmaxf(p[3], 0.0f), 512.0f);
    bx1[tid] = x1; by1[tid] = y1; bx2[tid] = x2; by2[tid] = y2;
    barea[tid] = __fmul_rn(__fsub_rn(x2, x1), __fsub_rn(y2, y1));
  }
  if (tid >= 64 && tid < 128) {
    float m; int nn, np;
    reduce_stats(ws, b, tid - 64, m, nn, np);
    if (tid == 64) {
      int ge = (m >= 0.7f) ? 1 : 0;
      s_npos = ge ? np : ws->pos_cnt[b];
      s_nneg = nn;
    }
  }

  int mp = min(ws->pos_cnt[b], GCAP);
  int mn = min(ws->neg_cnt[b], GCAP);
  int mpad = (mp + 255) & ~255;
  int npad = (mn + 255) & ~255;
  for (int i = tid; i < mpad; i += 256) pk[i] = (i < mp) ? ws->pos_key[b * GCAP + i] : 0ull;
  for (int i = tid; i < npad; i += 256) nk[i] = (i < mn) ? ws->neg_key[b * GCAP + i] : 0ull;
  if (tid < NS) { tpos[tid] = 0.0f; treg[tid] = 0.0f; }
  if (tid < 2 * NS) tneg[tid] = 0.0f;
  __syncthreads();

  int K = min(NS, s_npos);
  int rp = min(K, mp);
  int rn = min(min(2 * NS - K, s_nneg), mn);

  // --- pos ranks (each thread owns up to GCAP/256 candidates; j-sweep shared) ---
  {
    u64 ck[GCAP / 256]; int cr[GCAP / 256];
    int nc = mpad >> 8;
#pragma unroll
    for (int c = 0; c < GCAP / 256; c++) { ck[c] = 0; cr[c] = 0; }
    for (int c = 0; c < nc; c++) ck[c] = pk[tid + (c << 8)];
    for (int j = 0; j < mp; j++) {
      u64 v = pk[j];
#pragma unroll
      for (int c = 0; c < GCAP / 256; c++) cr[c] += (v > ck[c]) ? 1 : 0;
    }
    for (int c = 0; c < nc; c++)
      if (ck[c] != 0 && cr[c] < rp) selp[cr[c]] = (int)(~(u32)ck[c]);
  }
  // --- neg ranks ---
  {
    u64 ck[GCAP / 256]; int cr[GCAP / 256];
    int nc = npad >> 8;
#pragma unroll
    for (int c = 0; c < GCAP / 256; c++) { ck[c] = 0; cr[c] = 0; }
    for (int c = 0; c < nc; c++) ck[c] = nk[tid + (c << 8)];
    for (int j = 0; j < mn; j++) {
      u64 v = nk[j];
#pragma unroll
      for (int c = 0; c < GCAP / 256; c++) cr[c] += (v > ck[c]) ? 1 : 0;
    }
    for (int c = 0; c < nc; c++)
      if (ck[c] != 0 && cr[c] < rn) seln[cr[c]] = (int)(~(u32)ck[c]);
  }
  __syncthreads();

  const float PLO = 1e-7f;
  const float PHI = (float)(1.0 - 1e-7);
  if (tid < rp) {
    int a = selp[tid];
    float p = cls[((size_t)b * NA + a) * 2 + 0];
    p = fminf(fmaxf(p, PLO), PHI);
    tpos[tid] = -logf(p);
    float4 apf = ((const float4*)anchors)[a];
    float ax1 = apf.x, ay1 = apf.y, ax2 = apf.z, ay2 = apf.w;
    float aarea = __fmul_rn(__fsub_rn(ax2, ax1), __fsub_rn(ay2, ay1));
    // recompute IoU row + first-argmax with literal reference ops
    float bestv = -1.0f; int bestm = 0;
    for (int m = 0; m < NM; m++) {
      float iw = fmaxf(__fsub_rn(fminf(ax2, bx2[m]), fmaxf(ax1, bx1[m])), 0.0f);
      float ih = fmaxf(__fsub_rn(fminf(ay2, by2[m]), fmaxf(ay1, by1[m])), 0.0f);
      float inter = __fmul_rn(iw, ih);
      float ua = fmaxf(__fsub_rn(__fadd_rn(aarea, barea[m]), inter), 1e-8f);
      float v = __fdiv_rn(inter, ua);
      if (v > bestv) { bestv = v; bestm = m; }
    }
    float aw_ = __fsub_rn(ax2, ax1), ah_ = __fsub_rn(ay2, ay1);
    float acx = __fadd_rn(ax1, __fmul_rn(0.5f, aw_));
    float acy = __fadd_rn(ay1, __fmul_rn(0.5f, ah_));
    float gx1 = bx1[bestm], gy1 = by1[bestm], gx2 = bx2[bestm], gy2 = by2[bestm];
    float gw = __fsub_rn(gx2, gx1), gh = __fsub_rn(gy2, gy1);
    float gcx = __fadd_rn(gx1, __fmul_rn(0.5f, gw));
    float gcy = __fadd_rn(gy1, __fmul_rn(0.5f, gh));
    gw = fmaxf(gw, 1.0f); gh = fmaxf(gh, 1.0f);
    float t0 = __fdiv_rn(__fdiv_rn(__fsub_rn(gcx, acx), aw_), 0.1f);
    float t1 = __fdiv_rn(__fdiv_rn(__fsub_rn(gcy, acy), ah_), 0.1f);
    float t2 = __fdiv_rn(logf(__fdiv_rn(gw, aw_)), 0.2f);
    float t3 = __fdiv_rn(logf(__fdiv_rn(gh, ah_)), 0.2f);
    const float* rg = reg + ((size_t)b * NA + a) * 4;
    float tt[4] = {t0, t1, t2, t3};
    float s = 0.0f;
#pragma unroll
    for (int c = 0; c < 4; c++) {
      float d = fabsf(__fsub_rn(tt[c], rg[c]));
      float q = (d <= (float)(1.0 / 9.0)) ? __fmul_rn(__fmul_rn(4.5f, d), d)
                                          : __fsub_rn(d, (float)(0.5 / 9.0));
      s = __fadd_rn(s, q);
    }
    treg[tid] = s;
  }
  if (tid < rn) {
    int a = seln[tid];
    bool ispos = false;
    for (int i = 0; i < rp; i++) if (selp[i] == a) ispos = true;
    if (!ispos) {
      float p = cls[((size_t)b * NA + a) * 2 + 1];
      p = fminf(fmaxf(p, PLO), PHI);
      tneg[tid] = -logf(p);
    }
  }
  __syncthreads();
  if (tid == 0) {
    float cs = 0.0f;
    for (int i = 0; i < NS; i++) cs = __fadd_rn(cs, tpos[i]);
    for (int i = 0; i < 2 * NS; i++) cs = __fadd_rn(cs, tneg[i]);
    float rs = 0.0f;
    for (int i = 0; i < NS; i++) rs = __fadd_rn(rs, treg[i]);
    float ci = __fdiv_rn(cs, 64.0f);
    float ri = __fdiv_rn(__fmul_rn(rs, w[b * 4 + 0]), 64.0f);
    __hip_atomic_store(&ws->cls_bits[b], __float_as_uint(ci), __ATOMIC_RELEASE, __HIP_MEMORY_SCOPE_AGENT);
    __hip_atomic_store(&ws->reg_bits[b], __float_as_uint(ri), __ATOMIC_RELEASE, __HIP_MEMORY_SCOPE_AGENT);
    int old = __hip_atomic_fetch_add(&ws->done, 1, __ATOMIC_ACQ_REL, __HIP_MEMORY_SCOPE_AGENT);
    if (old == NB - 1) {  // last image: independent relaxed loads, then b-ordered sum
      u32 cb[NB], rb[NB];
#pragma unroll
      for (int j = 0; j < NB; j++) {
        cb[j] = __hip_atomic_load(&ws->cls_bits[j], __ATOMIC_RELAXED, __HIP_MEMORY_SCOPE_AGENT);
        rb[j] = __hip_atomic_load(&ws->reg_bits[j], __ATOMIC_RELAXED, __HIP_MEMORY_SCOPE_AGENT);
      }
      float c = 0.0f, r = 0.0f;
#pragma unroll
      for (int j = 0; j < NB; j++) {
        c = __fadd_rn(c, __uint_as_float(cb[j]));
        r = __fadd_rn(r, __uint_as_float(rb[j]));
      }
      out[0] = __fdiv_rn(c, 16.0f);
      out[1] = __fdiv_rn(r, 16.0f);
    }
  }
}

extern "C" void kernel_launch(void* const* d_in, const int* in_sizes, int n_in,
                              void* d_out, int out_size, void* d_ws, size_t ws_size,
                              hipStream_t stream) {
  const float* cls = (const float*)d_in[0];
  const float* reg = (const float*)d_in[1];
  const float* anchors = (const float*)d_in[2];  // (1, A, 4)
  const float* ann = (const float*)d_in[3];      // (B, M, 5)
  const float* w = (const float*)d_in[4];        // (B, 4)
  float* out = (float*)d_out;
  if (ws_size < sizeof(WS)) return;
  WS* ws = (WS*)d_ws;

  hipLaunchKernelGGL(k_iou, dim3(BLKI, NB), dim3(256), 0, stream, anchors, ann, ws);
  hipLaunchKernelGGL(k_push, dim3(BLKI, NB), dim3(256), 0, stream, ws);
  hipLaunchKernelGGL(k_select, dim3(NB), dim3(256), 0, stream, cls, reg, anchors, ann, w, ws, out);
}